// Round 1
// baseline (13233.966 us; speedup 1.0000x reference)
//
#include <hip/hip_runtime.h>
#include <stdint.h>

#define B_  64
#define T_  512
#define IN_ 512
#define H_  1024
#define O_  512

typedef short  short8 __attribute__((ext_vector_type(8)));
typedef float  f32x4  __attribute__((ext_vector_type(4)));
typedef unsigned int uint32;

// fp32 -> bf16, round-to-nearest-even
__device__ __forceinline__ unsigned short f2bf(float f) {
  uint32 u = __builtin_bit_cast(uint32, f);
  uint32 r = u + 0x7fffu + ((u >> 16) & 1u);
  return (unsigned short)(r >> 16);
}
__device__ __forceinline__ float bf2f(unsigned short h) {
  uint32 u = ((uint32)h) << 16;
  return __builtin_bit_cast(float, u);
}

__device__ __forceinline__ f32x4 mfma_bf16(short8 a, short8 b, f32x4 c) {
  return __builtin_amdgcn_mfma_f32_16x16x32_bf16(a, b, c, 0, 0, 0);
}

// ---------------------------------------------------------------------------
// GEMM1: xwH[b][t][n] = bf16( x[b][t][:] @ W_xh[:, n] + b_h[n] )
// A (x) split hi/lo (2-term) for ~fp32 input precision; B in bf16.
// M = 32768 rows (m = b*512+t, natural), K = 512, N = 1024. 64x64 tiles.
// ---------------------------------------------------------------------------
__global__ __launch_bounds__(256) void g1_xh(
    const float* __restrict__ x, const float* __restrict__ Wxh,
    const float* __restrict__ bh, unsigned short* __restrict__ xwH)
{
  const int blk = blockIdx.x;
  const int mt = blk >> 4;          // 512 m-tiles
  const int nt = blk & 15;          // 16 n-tiles
  const int m0 = mt * 64, n0 = nt * 64;
  const int tid = threadIdx.x;
  const int wave = tid >> 6, lane = tid & 63;
  const int l15 = lane & 15, l4 = lane >> 4;

  __shared__ unsigned short sAhi[64 * 40];   // [row][k], pad 32->40
  __shared__ unsigned short sAlo[64 * 40];
  __shared__ unsigned short sB[64 * 40];     // [n][k] (transposed)

  f32x4 acc[4] = { {0.f,0.f,0.f,0.f}, {0.f,0.f,0.f,0.f},
                   {0.f,0.f,0.f,0.f}, {0.f,0.f,0.f,0.f} };

  for (int kk = 0; kk < IN_ / 32; ++kk) {
    const int k0 = kk * 32;
    // stage A: 64 rows x 32 k fp32 -> hi/lo bf16
#pragma unroll
    for (int q = 0; q < 2; ++q) {
      const int v = tid + q * 256;           // 0..511
      const int row = v >> 3;
      const int c4 = (v & 7) * 4;
      const float4 av = *(const float4*)(x + (size_t)(m0 + row) * IN_ + k0 + c4);
      unsigned short h0 = f2bf(av.x), h1 = f2bf(av.y), h2 = f2bf(av.z), h3 = f2bf(av.w);
      unsigned short g0 = f2bf(av.x - bf2f(h0)), g1 = f2bf(av.y - bf2f(h1));
      unsigned short g2 = f2bf(av.z - bf2f(h2)), g3 = f2bf(av.w - bf2f(h3));
      uint32* dh = (uint32*)&sAhi[row * 40 + c4];
      dh[0] = (uint32)h0 | ((uint32)h1 << 16);
      dh[1] = (uint32)h2 | ((uint32)h3 << 16);
      uint32* dl = (uint32*)&sAlo[row * 40 + c4];
      dl[0] = (uint32)g0 | ((uint32)g1 << 16);
      dl[1] = (uint32)g2 | ((uint32)g3 << 16);
    }
    // stage B transposed: W_xh[k0+k][n0+n] -> sB[n][k]
#pragma unroll
    for (int q = 0; q < 2; ++q) {
      const int v = tid + q * 256;
      const int k = v >> 4;
      const int n4 = (v & 15) * 4;
      const float4 bv = *(const float4*)(Wxh + (size_t)(k0 + k) * H_ + n0 + n4);
      sB[(n4 + 0) * 40 + k] = f2bf(bv.x);
      sB[(n4 + 1) * 40 + k] = f2bf(bv.y);
      sB[(n4 + 2) * 40 + k] = f2bf(bv.z);
      sB[(n4 + 3) * 40 + k] = f2bf(bv.w);
    }
    __syncthreads();
    const int arow = wave * 16 + l15;
    const short8 ahi = *(const short8*)&sAhi[arow * 40 + l4 * 8];
    const short8 alo = *(const short8*)&sAlo[arow * 40 + l4 * 8];
#pragma unroll
    for (int ct = 0; ct < 4; ++ct) {
      const short8 bf = *(const short8*)&sB[(ct * 16 + l15) * 40 + l4 * 8];
      acc[ct] = mfma_bf16(ahi, bf, acc[ct]);
      acc[ct] = mfma_bf16(alo, bf, acc[ct]);
    }
    __syncthreads();
  }
  // epilogue: + b_h, store bf16
#pragma unroll
  for (int ct = 0; ct < 4; ++ct) {
    const int n = n0 + ct * 16 + l15;
    const float bias = bh[n];
#pragma unroll
    for (int i = 0; i < 4; ++i) {
      const int m = m0 + wave * 16 + l4 * 4 + i;
      xwH[(size_t)m * H_ + n] = f2bf(acc[ct][i] + bias);
    }
  }
}

// ---------------------------------------------------------------------------
// Recurrence: persistent kernel, 128 blocks = 4 batch-groups x 32 col-groups.
// Each block: rows rb0..rb0+15 (batch), cols c0..c0+31 (hidden). 4 waves split
// K=1024 into 256-chunks; W_hh bf16 fragments live in registers all 512 steps.
// h_t (hi) overwrites the consumed xw slot in place (1:1 element aliasing);
// h_lo ping-pongs in a small side buffer. Per-group 32-block spin barrier.
// ---------------------------------------------------------------------------
#define GCn 32
#define NB  16
#define NC  32

__global__ __launch_bounds__(256) void rnn_rec(
    const float* __restrict__ Whh,
    unsigned short* __restrict__ xwH,    // [64][512][1024] bf16: in xw, out h
    unsigned short* __restrict__ rotlo,  // [2][64][1024] bf16
    int* __restrict__ ctrl)
{
  const int blk = blockIdx.x;          // 0..127
  const int gb = blk >> 5;             // 0..3
  const int gc = blk & 31;             // 0..31
  const int rb0 = gb * NB;
  const int c0 = gc * NC;
  const int tid = threadIdx.x;
  const int wave = tid >> 6, lane = tid & 63;
  const int l15 = lane & 15, l4 = lane >> 4;
  const int kp0 = wave * 256;          // K-range of this wave

  __shared__ float red[4][NB][NC];

  // --- load W_hh fragments (bf16) into registers, kept for all 512 steps ---
  short8 Wf[8][2];
#pragma unroll
  for (int ks = 0; ks < 8; ++ks) {
#pragma unroll
    for (int ct = 0; ct < 2; ++ct) {
      const int n = c0 + ct * 16 + l15;
#pragma unroll
      for (int j = 0; j < 8; ++j) {
        const int k = kp0 + ks * 32 + l4 * 8 + j;
        Wf[ks][ct][j] = (short)f2bf(Whh[(size_t)k * H_ + n]);
      }
    }
  }

  int* cnt = ctrl + gb * 32;           // 128 B apart per group
  int* gen = ctrl + 128 + gb * 32;

  for (int t = 0; t < T_; ++t) {
    // prefetch this block's xw values (slot t; only ever written by G1)
    const int e0 = tid, e1 = tid + 256;
    const int b0r = rb0 + (e0 >> 5), n0e = c0 + (e0 & 31);
    const int b1r = rb0 + (e1 >> 5), n1e = c0 + (e1 & 31);
    const size_t a0 = (size_t)(b0r * T_ + t) * H_ + n0e;
    const size_t a1 = (size_t)(b1r * T_ + t) * H_ + n1e;
    const float xw0 = bf2f(xwH[a0]);
    const float xw1 = bf2f(xwH[a1]);

    f32x4 acc0 = {0.f,0.f,0.f,0.f}, acc1 = {0.f,0.f,0.f,0.f};
    if (t > 0) {
      const unsigned short* lsrc = rotlo + (size_t)((t - 1) & 1) * (B_ * H_);
      const int brow = rb0 + l15;
      short8 Ahi[8], Alo[8];
#pragma unroll
      for (int ks = 0; ks < 8; ++ks) {
        const int k = kp0 + ks * 32 + l4 * 8;
        Ahi[ks] = *(const short8*)(xwH + (size_t)(brow * T_ + (t - 1)) * H_ + k);
        Alo[ks] = *(const short8*)(lsrc + (size_t)brow * H_ + k);
      }
#pragma unroll
      for (int ks = 0; ks < 8; ++ks) {
        acc0 = mfma_bf16(Ahi[ks], Wf[ks][0], acc0);
        acc0 = mfma_bf16(Alo[ks], Wf[ks][0], acc0);
        acc1 = mfma_bf16(Ahi[ks], Wf[ks][1], acc1);
        acc1 = mfma_bf16(Alo[ks], Wf[ks][1], acc1);
      }
    }
    // write K-partials (C layout: col=lane&15, row=(lane>>4)*4+i)
#pragma unroll
    for (int i = 0; i < 4; ++i) {
      red[wave][l4 * 4 + i][l15]      = acc0[i];
      red[wave][l4 * 4 + i][16 + l15] = acc1[i];
    }
    __syncthreads();
    // reduce 4 partials + xw, tanh, split hi/lo, store
    {
      const int r0 = e0 >> 5, cc0 = e0 & 31;
      const int r1 = e1 >> 5, cc1 = e1 & 31;
      const float s0 = red[0][r0][cc0] + red[1][r0][cc0] + red[2][r0][cc0] + red[3][r0][cc0];
      const float s1 = red[0][r1][cc1] + red[1][r1][cc1] + red[2][r1][cc1] + red[3][r1][cc1];
      const float h0 = tanhf(s0 + xw0);
      const float h1 = tanhf(s1 + xw1);
      const unsigned short hh0 = f2bf(h0);
      const unsigned short hh1 = f2bf(h1);
      const unsigned short hl0 = f2bf(h0 - bf2f(hh0));
      const unsigned short hl1 = f2bf(h1 - bf2f(hh1));
      xwH[a0] = hh0;                       // in-place: h_t hi over consumed xw
      xwH[a1] = hh1;
      unsigned short* ldst = rotlo + (size_t)(t & 1) * (B_ * H_);
      ldst[(size_t)b0r * H_ + n0e] = hl0;
      ldst[(size_t)b1r * H_ + n1e] = hl1;
    }
    // --- per-group grid barrier (device-scope, cross-XCD safe) ---
    __threadfence();                       // release: flush h stores
    __syncthreads();
    if (tid == 0) {
      const int g = __hip_atomic_load(gen, __ATOMIC_RELAXED, __HIP_MEMORY_SCOPE_AGENT);
      const int a = __hip_atomic_fetch_add(cnt, 1, __ATOMIC_ACQ_REL, __HIP_MEMORY_SCOPE_AGENT);
      if (a == GCn - 1) {
        __hip_atomic_store(cnt, 0, __ATOMIC_RELAXED, __HIP_MEMORY_SCOPE_AGENT);
        __hip_atomic_fetch_add(gen, 1, __ATOMIC_RELEASE, __HIP_MEMORY_SCOPE_AGENT);
      } else {
        while (__hip_atomic_load(gen, __ATOMIC_RELAXED, __HIP_MEMORY_SCOPE_AGENT) == g) {
          __builtin_amdgcn_s_sleep(4);
        }
      }
    }
    __syncthreads();
    __threadfence();                       // acquire: invalidate stale L1/L2
  }
}

// ---------------------------------------------------------------------------
// GEMM3: out[m][n] = Hm[m][:] @ W_hy[:, n] + b_y[n]   (m = b*512+t, natural)
// M = 32768, K = 1024, N = 512. A already bf16 (= h history, in xw buffer).
// ---------------------------------------------------------------------------
__global__ __launch_bounds__(256) void g3_hy(
    const unsigned short* __restrict__ Hm, const float* __restrict__ Why,
    const float* __restrict__ by, float* __restrict__ out)
{
  const int blk = blockIdx.x;
  const int mt = blk >> 3;          // 512 m-tiles
  const int nt = blk & 7;           // 8 n-tiles
  const int m0 = mt * 64, n0 = nt * 64;
  const int tid = threadIdx.x;
  const int wave = tid >> 6, lane = tid & 63;
  const int l15 = lane & 15, l4 = lane >> 4;

  __shared__ unsigned short sA[64 * 40];
  __shared__ unsigned short sB[64 * 40];

  f32x4 acc[4] = { {0.f,0.f,0.f,0.f}, {0.f,0.f,0.f,0.f},
                   {0.f,0.f,0.f,0.f}, {0.f,0.f,0.f,0.f} };

  for (int kk = 0; kk < H_ / 32; ++kk) {
    const int k0 = kk * 32;
    // stage A: 64 rows x 32 bf16 (256 chunks of 8)
    {
      const int row = tid >> 2;
      const int c8 = (tid & 3) * 8;
      const short8 v = *(const short8*)(Hm + (size_t)(m0 + row) * H_ + k0 + c8);
      *(short8*)&sA[row * 40 + c8] = v;
    }
    // stage B transposed: W_hy[k0+k][n0+n] -> sB[n][k]
#pragma unroll
    for (int q = 0; q < 2; ++q) {
      const int v = tid + q * 256;
      const int k = v >> 4;
      const int n4 = (v & 15) * 4;
      const float4 bv = *(const float4*)(Why + (size_t)(k0 + k) * O_ + n0 + n4);
      sB[(n4 + 0) * 40 + k] = f2bf(bv.x);
      sB[(n4 + 1) * 40 + k] = f2bf(bv.y);
      sB[(n4 + 2) * 40 + k] = f2bf(bv.z);
      sB[(n4 + 3) * 40 + k] = f2bf(bv.w);
    }
    __syncthreads();
    const short8 a = *(const short8*)&sA[(wave * 16 + l15) * 40 + l4 * 8];
#pragma unroll
    for (int ct = 0; ct < 4; ++ct) {
      const short8 bf = *(const short8*)&sB[(ct * 16 + l15) * 40 + l4 * 8];
      acc[ct] = mfma_bf16(a, bf, acc[ct]);
    }
    __syncthreads();
  }
#pragma unroll
  for (int ct = 0; ct < 4; ++ct) {
    const int n = n0 + ct * 16 + l15;
    const float bias = by[n];
#pragma unroll
    for (int i = 0; i < 4; ++i) {
      const int m = m0 + wave * 16 + l4 * 4 + i;
      out[(size_t)m * O_ + n] = acc[ct][i] + bias;   // out[b][t][o], m=b*512+t
    }
  }
}

// ---------------------------------------------------------------------------
extern "C" void kernel_launch(void* const* d_in, const int* in_sizes, int n_in,
                              void* d_out, int out_size, void* d_ws, size_t ws_size,
                              hipStream_t stream) {
  const float* x   = (const float*)d_in[0];
  const float* Wxh = (const float*)d_in[1];
  const float* Whh = (const float*)d_in[2];
  const float* bh  = (const float*)d_in[3];
  const float* Why = (const float*)d_in[4];
  const float* by  = (const float*)d_in[5];
  float* out = (float*)d_out;

  // ws layout: xwH (67,108,864 B) | rotlo (262,144 B) | ctrl (1,024 B)
  unsigned short* xwH   = (unsigned short*)d_ws;
  unsigned short* rotlo = (unsigned short*)((char*)d_ws + 67108864);
  int*            ctrl  = (int*)((char*)d_ws + 67108864 + 262144);

  hipMemsetAsync(ctrl, 0, 1024, stream);
  g1_xh<<<8192, 256, 0, stream>>>(x, Wxh, bh, xwH);
  rnn_rec<<<128, 256, 0, stream>>>(Whh, xwH, rotlo, ctrl);
  g3_hy<<<4096, 256, 0, stream>>>(xwH, Why, by, out);
}

// Round 2
// 3833.199 us; speedup vs baseline: 3.4525x; 3.4525x over previous
//
#include <hip/hip_runtime.h>
#include <stdint.h>

#define B_  64
#define T_  512
#define IN_ 512
#define H_  1024
#define O_  512

typedef short  short8 __attribute__((ext_vector_type(8)));
typedef float  f32x4  __attribute__((ext_vector_type(4)));
typedef unsigned int uint32;

// fp32 -> bf16, round-to-nearest-even
__device__ __forceinline__ unsigned short f2bf(float f) {
  uint32 u = __builtin_bit_cast(uint32, f);
  uint32 r = u + 0x7fffu + ((u >> 16) & 1u);
  return (unsigned short)(r >> 16);
}
__device__ __forceinline__ float bf2f(unsigned short h) {
  uint32 u = ((uint32)h) << 16;
  return __builtin_bit_cast(float, u);
}

__device__ __forceinline__ f32x4 mfma_bf16(short8 a, short8 b, f32x4 c) {
  return __builtin_amdgcn_mfma_f32_16x16x32_bf16(a, b, c, 0, 0, 0);
}

// device-coherent (agent-scope, relaxed) 16B load as 2x u64 — sc-bit loads
// bypass the incoherent L1/L2 and read the LLC. No cache-maintenance ops.
__device__ __forceinline__ short8 aload16(const unsigned short* p) {
  struct U { unsigned long long a, b; } u;
  u.a = __hip_atomic_load((const unsigned long long*)p,
                          __ATOMIC_RELAXED, __HIP_MEMORY_SCOPE_AGENT);
  u.b = __hip_atomic_load((const unsigned long long*)(p + 4),
                          __ATOMIC_RELAXED, __HIP_MEMORY_SCOPE_AGENT);
  return __builtin_bit_cast(short8, u);
}

// ---------------------------------------------------------------------------
// GEMM1: xwH[b][t][n] = bf16( x[b][t][:] @ W_xh[:, n] + b_h[n] )
// A (x) split hi/lo (2-term) for ~fp32 input precision; B in bf16.
// M = 32768 rows (m = b*512+t, natural), K = 512, N = 1024. 64x64 tiles.
// ---------------------------------------------------------------------------
__global__ __launch_bounds__(256) void g1_xh(
    const float* __restrict__ x, const float* __restrict__ Wxh,
    const float* __restrict__ bh, unsigned short* __restrict__ xwH)
{
  const int blk = blockIdx.x;
  const int mt = blk >> 4;          // 512 m-tiles
  const int nt = blk & 15;          // 16 n-tiles
  const int m0 = mt * 64, n0 = nt * 64;
  const int tid = threadIdx.x;
  const int wave = tid >> 6, lane = tid & 63;
  const int l15 = lane & 15, l4 = lane >> 4;

  __shared__ unsigned short sAhi[64 * 40];   // [row][k], pad 32->40
  __shared__ unsigned short sAlo[64 * 40];
  __shared__ unsigned short sB[64 * 40];     // [n][k] (transposed)

  f32x4 acc[4] = { {0.f,0.f,0.f,0.f}, {0.f,0.f,0.f,0.f},
                   {0.f,0.f,0.f,0.f}, {0.f,0.f,0.f,0.f} };

  for (int kk = 0; kk < IN_ / 32; ++kk) {
    const int k0 = kk * 32;
#pragma unroll
    for (int q = 0; q < 2; ++q) {
      const int v = tid + q * 256;           // 0..511
      const int row = v >> 3;
      const int c4 = (v & 7) * 4;
      const float4 av = *(const float4*)(x + (size_t)(m0 + row) * IN_ + k0 + c4);
      unsigned short h0 = f2bf(av.x), h1 = f2bf(av.y), h2 = f2bf(av.z), h3 = f2bf(av.w);
      unsigned short g0 = f2bf(av.x - bf2f(h0)), g1 = f2bf(av.y - bf2f(h1));
      unsigned short g2 = f2bf(av.z - bf2f(h2)), g3 = f2bf(av.w - bf2f(h3));
      uint32* dh = (uint32*)&sAhi[row * 40 + c4];
      dh[0] = (uint32)h0 | ((uint32)h1 << 16);
      dh[1] = (uint32)h2 | ((uint32)h3 << 16);
      uint32* dl = (uint32*)&sAlo[row * 40 + c4];
      dl[0] = (uint32)g0 | ((uint32)g1 << 16);
      dl[1] = (uint32)g2 | ((uint32)g3 << 16);
    }
#pragma unroll
    for (int q = 0; q < 2; ++q) {
      const int v = tid + q * 256;
      const int k = v >> 4;
      const int n4 = (v & 15) * 4;
      const float4 bv = *(const float4*)(Wxh + (size_t)(k0 + k) * H_ + n0 + n4);
      sB[(n4 + 0) * 40 + k] = f2bf(bv.x);
      sB[(n4 + 1) * 40 + k] = f2bf(bv.y);
      sB[(n4 + 2) * 40 + k] = f2bf(bv.z);
      sB[(n4 + 3) * 40 + k] = f2bf(bv.w);
    }
    __syncthreads();
    const int arow = wave * 16 + l15;
    const short8 ahi = *(const short8*)&sAhi[arow * 40 + l4 * 8];
    const short8 alo = *(const short8*)&sAlo[arow * 40 + l4 * 8];
#pragma unroll
    for (int ct = 0; ct < 4; ++ct) {
      const short8 bf = *(const short8*)&sB[(ct * 16 + l15) * 40 + l4 * 8];
      acc[ct] = mfma_bf16(ahi, bf, acc[ct]);
      acc[ct] = mfma_bf16(alo, bf, acc[ct]);
    }
    __syncthreads();
  }
#pragma unroll
  for (int ct = 0; ct < 4; ++ct) {
    const int n = n0 + ct * 16 + l15;
    const float bias = bh[n];
#pragma unroll
    for (int i = 0; i < 4; ++i) {
      const int m = m0 + wave * 16 + l4 * 4 + i;
      xwH[(size_t)m * H_ + n] = f2bf(acc[ct][i] + bias);
    }
  }
}

// ---------------------------------------------------------------------------
// Recurrence: persistent kernel, 128 blocks = 4 batch-groups x 32 col-groups.
// Each block: rows rb0..rb0+15 (batch), cols c0..c0+31 (hidden). 4 waves split
// K=1024 into 256-chunks; W_hh bf16 fragments live in registers all 512 steps.
// h exchange goes through device-coherent (sc-bit) atomic loads/stores ONLY —
// no __threadfence (which on gfx950 = cache-wide buffer_wbl2/buffer_inv, the
// round-1 25us/step killer). Barrier = monotonic counter, relaxed atomics,
// preceded by s_waitcnt vmcnt(0) (release without the L2 flush).
// ---------------------------------------------------------------------------
#define GCn 32
#define NB  16
#define NC  32

__global__ __launch_bounds__(256) void rnn_rec(
    const float* __restrict__ Whh,
    unsigned short* __restrict__ xwH,    // [64][512][1024] bf16: in xw, out h
    unsigned short* __restrict__ rotlo,  // [2][64][1024] bf16
    int* __restrict__ ctrl)
{
  const int blk = blockIdx.x;          // 0..127
  const int gb = blk >> 5;             // 0..3
  const int gc = blk & 31;             // 0..31
  const int rb0 = gb * NB;
  const int c0 = gc * NC;
  const int tid = threadIdx.x;
  const int wave = tid >> 6, lane = tid & 63;
  const int l15 = lane & 15, l4 = lane >> 4;
  const int kp0 = wave * 256;          // K-range of this wave

  __shared__ __align__(16) float red[4][NB][NC];

  // --- W_hh bf16 fragments in registers for all 512 steps ---
  short8 Wf[8][2];
#pragma unroll
  for (int ks = 0; ks < 8; ++ks) {
#pragma unroll
    for (int ct = 0; ct < 2; ++ct) {
      const int n = c0 + ct * 16 + l15;
#pragma unroll
      for (int j = 0; j < 8; ++j) {
        const int k = kp0 + ks * 32 + l4 * 8 + j;
        Wf[ks][ct][j] = (short)f2bf(Whh[(size_t)k * H_ + n]);
      }
    }
  }

  int* cnt = ctrl + gb * 64;           // 256 B apart per batch-group

  // epilogue mapping: thread -> (row r, col-pair p2) of the 16x32 tile
  const int er = tid >> 4;             // 0..15
  const int p2 = (tid & 15) * 2;       // 0,2,..,30

  for (int t = 0; t < T_; ++t) {
    // xw for this step (plain load — written only by g1 / this block)
    const size_t aXW = ((size_t)((rb0 + er) * T_ + t)) * H_ + c0 + p2;
    const uint32 xwu = *(const uint32*)(xwH + aXW);

    f32x4 acc0 = {0.f,0.f,0.f,0.f}, acc1 = {0.f,0.f,0.f,0.f};
    if (t > 0) {
      const unsigned short* lsrc = rotlo + (size_t)((t - 1) & 1) * (B_ * H_);
      const int brow = rb0 + l15;
      short8 Ahi[8], Alo[8];
#pragma unroll
      for (int ks = 0; ks < 8; ++ks) {
        const int k = kp0 + ks * 32 + l4 * 8;
        Ahi[ks] = aload16(xwH + (size_t)(brow * T_ + (t - 1)) * H_ + k);
        Alo[ks] = aload16(lsrc + (size_t)brow * H_ + k);
      }
#pragma unroll
      for (int ks = 0; ks < 8; ++ks) {
        acc0 = mfma_bf16(Ahi[ks], Wf[ks][0], acc0);
        acc0 = mfma_bf16(Alo[ks], Wf[ks][0], acc0);
        acc1 = mfma_bf16(Ahi[ks], Wf[ks][1], acc1);
        acc1 = mfma_bf16(Alo[ks], Wf[ks][1], acc1);
      }
    }
    // K-partials to LDS (C layout: col=lane&15, row=(lane>>4)*4+i)
#pragma unroll
    for (int i = 0; i < 4; ++i) {
      red[wave][l4 * 4 + i][l15]      = acc0[i];
      red[wave][l4 * 4 + i][16 + l15] = acc1[i];
    }
    __syncthreads();
    // reduce 4 partials + xw, tanh, split hi/lo, device-coherent store
    {
      float sa = 0.f, sb = 0.f;
#pragma unroll
      for (int w = 0; w < 4; ++w) {
        const float2 v = *(const float2*)&red[w][er][p2];
        sa += v.x; sb += v.y;
      }
      const float h0 = tanhf(sa + bf2f((unsigned short)(xwu & 0xffffu)));
      const float h1 = tanhf(sb + bf2f((unsigned short)(xwu >> 16)));
      const unsigned short hh0 = f2bf(h0), hh1 = f2bf(h1);
      const unsigned short hl0 = f2bf(h0 - bf2f(hh0));
      const unsigned short hl1 = f2bf(h1 - bf2f(hh1));
      const uint32 hi32 = (uint32)hh0 | ((uint32)hh1 << 16);
      const uint32 lo32 = (uint32)hl0 | ((uint32)hl1 << 16);
      __hip_atomic_store((uint32*)(xwH + aXW), hi32,
                         __ATOMIC_RELAXED, __HIP_MEMORY_SCOPE_AGENT);
      unsigned short* ldst = rotlo + (size_t)(t & 1) * (B_ * H_);
      __hip_atomic_store((uint32*)(ldst + (size_t)(rb0 + er) * H_ + c0 + p2), lo32,
                         __ATOMIC_RELAXED, __HIP_MEMORY_SCOPE_AGENT);
    }
    // --- per-group barrier: drain stores, arrive, poll monotonic counter ---
    asm volatile("s_waitcnt vmcnt(0)" ::: "memory");
    __syncthreads();                    // all waves' stores drained
    if (tid == 0) {
      __hip_atomic_fetch_add(cnt, 1, __ATOMIC_RELAXED, __HIP_MEMORY_SCOPE_AGENT);
      const int want = GCn * (t + 1);
      while (__hip_atomic_load(cnt, __ATOMIC_RELAXED, __HIP_MEMORY_SCOPE_AGENT) < want) {
        __builtin_amdgcn_s_sleep(2);
      }
    }
    __syncthreads();
  }
}

// ---------------------------------------------------------------------------
// GEMM3: out[m][n] = Hm[m][:] @ W_hy[:, n] + b_y[n]   (m = b*512+t, natural)
// M = 32768, K = 1024, N = 512. A already bf16 (= h history, in xw buffer).
// ---------------------------------------------------------------------------
__global__ __launch_bounds__(256) void g3_hy(
    const unsigned short* __restrict__ Hm, const float* __restrict__ Why,
    const float* __restrict__ by, float* __restrict__ out)
{
  const int blk = blockIdx.x;
  const int mt = blk >> 3;          // 512 m-tiles
  const int nt = blk & 7;           // 8 n-tiles
  const int m0 = mt * 64, n0 = nt * 64;
  const int tid = threadIdx.x;
  const int wave = tid >> 6, lane = tid & 63;
  const int l15 = lane & 15, l4 = lane >> 4;

  __shared__ unsigned short sA[64 * 40];
  __shared__ unsigned short sB[64 * 40];

  f32x4 acc[4] = { {0.f,0.f,0.f,0.f}, {0.f,0.f,0.f,0.f},
                   {0.f,0.f,0.f,0.f}, {0.f,0.f,0.f,0.f} };

  for (int kk = 0; kk < H_ / 32; ++kk) {
    const int k0 = kk * 32;
    {
      const int row = tid >> 2;
      const int c8 = (tid & 3) * 8;
      const short8 v = *(const short8*)(Hm + (size_t)(m0 + row) * H_ + k0 + c8);
      *(short8*)&sA[row * 40 + c8] = v;
    }
#pragma unroll
    for (int q = 0; q < 2; ++q) {
      const int v = tid + q * 256;
      const int k = v >> 4;
      const int n4 = (v & 15) * 4;
      const float4 bv = *(const float4*)(Why + (size_t)(k0 + k) * O_ + n0 + n4);
      sB[(n4 + 0) * 40 + k] = f2bf(bv.x);
      sB[(n4 + 1) * 40 + k] = f2bf(bv.y);
      sB[(n4 + 2) * 40 + k] = f2bf(bv.z);
      sB[(n4 + 3) * 40 + k] = f2bf(bv.w);
    }
    __syncthreads();
    const short8 a = *(const short8*)&sA[(wave * 16 + l15) * 40 + l4 * 8];
#pragma unroll
    for (int ct = 0; ct < 4; ++ct) {
      const short8 bf = *(const short8*)&sB[(ct * 16 + l15) * 40 + l4 * 8];
      acc[ct] = mfma_bf16(a, bf, acc[ct]);
    }
    __syncthreads();
  }
#pragma unroll
  for (int ct = 0; ct < 4; ++ct) {
    const int n = n0 + ct * 16 + l15;
    const float bias = by[n];
#pragma unroll
    for (int i = 0; i < 4; ++i) {
      const int m = m0 + wave * 16 + l4 * 4 + i;
      out[(size_t)m * O_ + n] = acc[ct][i] + bias;
    }
  }
}

// ---------------------------------------------------------------------------
extern "C" void kernel_launch(void* const* d_in, const int* in_sizes, int n_in,
                              void* d_out, int out_size, void* d_ws, size_t ws_size,
                              hipStream_t stream) {
  const float* x   = (const float*)d_in[0];
  const float* Wxh = (const float*)d_in[1];
  const float* Whh = (const float*)d_in[2];
  const float* bh  = (const float*)d_in[3];
  const float* Why = (const float*)d_in[4];
  const float* by  = (const float*)d_in[5];
  float* out = (float*)d_out;

  // ws layout: xwH (67,108,864 B) | rotlo (262,144 B) | ctrl (1,024 B)
  unsigned short* xwH   = (unsigned short*)d_ws;
  unsigned short* rotlo = (unsigned short*)((char*)d_ws + 67108864);
  int*            ctrl  = (int*)((char*)d_ws + 67108864 + 262144);

  hipMemsetAsync(ctrl, 0, 1024, stream);
  g1_xh<<<8192, 256, 0, stream>>>(x, Wxh, bh, xwH);
  rnn_rec<<<128, 256, 0, stream>>>(Whh, xwH, rotlo, ctrl);
  g3_hy<<<4096, 256, 0, stream>>>(xwH, Why, by, out);
}

// Round 3
// 3544.594 us; speedup vs baseline: 3.7336x; 1.0814x over previous
//
#include <hip/hip_runtime.h>
#include <stdint.h>

#define B_  64
#define T_  512
#define IN_ 512
#define H_  1024
#define O_  512

typedef short  short8 __attribute__((ext_vector_type(8)));
typedef float  f32x4  __attribute__((ext_vector_type(4)));
typedef unsigned int uint32;
typedef unsigned long long u64;

// fp32 -> bf16, round-to-nearest-even
__device__ __forceinline__ unsigned short f2bf(float f) {
  uint32 u = __builtin_bit_cast(uint32, f);
  uint32 r = u + 0x7fffu + ((u >> 16) & 1u);
  return (unsigned short)(r >> 16);
}
__device__ __forceinline__ float bf2f(unsigned short h) {
  uint32 u = ((uint32)h) << 16;
  return __builtin_bit_cast(float, u);
}

__device__ __forceinline__ f32x4 mfma_bf16(short8 a, short8 b, f32x4 c) {
  return __builtin_amdgcn_mfma_f32_16x16x32_bf16(a, b, c, 0, 0, 0);
}

// device-coherent (agent-scope, relaxed) 16B load as 2x u64 — sc-bit loads
// bypass the incoherent L1/L2 and read the LLC. No cache-maintenance ops.
__device__ __forceinline__ short8 aload16(const unsigned short* p) {
  struct U { u64 a, b; } u;
  u.a = __hip_atomic_load((const u64*)p, __ATOMIC_RELAXED, __HIP_MEMORY_SCOPE_AGENT);
  u.b = __hip_atomic_load((const u64*)(p + 4), __ATOMIC_RELAXED, __HIP_MEMORY_SCOPE_AGENT);
  return __builtin_bit_cast(short8, u);
}

// ---------------------------------------------------------------------------
// GEMM1: xwH[b][t][n] = bf16( x[b][t][:] @ W_xh[:, n] + b_h[n] )
// ---------------------------------------------------------------------------
__global__ __launch_bounds__(256) void g1_xh(
    const float* __restrict__ x, const float* __restrict__ Wxh,
    const float* __restrict__ bh, unsigned short* __restrict__ xwH)
{
  const int blk = blockIdx.x;
  const int mt = blk >> 4;          // 512 m-tiles
  const int nt = blk & 15;          // 16 n-tiles
  const int m0 = mt * 64, n0 = nt * 64;
  const int tid = threadIdx.x;
  const int wave = tid >> 6, lane = tid & 63;
  const int l15 = lane & 15, l4 = lane >> 4;

  __shared__ unsigned short sAhi[64 * 40];
  __shared__ unsigned short sAlo[64 * 40];
  __shared__ unsigned short sB[64 * 40];

  f32x4 acc[4] = { {0.f,0.f,0.f,0.f}, {0.f,0.f,0.f,0.f},
                   {0.f,0.f,0.f,0.f}, {0.f,0.f,0.f,0.f} };

  for (int kk = 0; kk < IN_ / 32; ++kk) {
    const int k0 = kk * 32;
#pragma unroll
    for (int q = 0; q < 2; ++q) {
      const int v = tid + q * 256;
      const int row = v >> 3;
      const int c4 = (v & 7) * 4;
      const float4 av = *(const float4*)(x + (size_t)(m0 + row) * IN_ + k0 + c4);
      unsigned short h0 = f2bf(av.x), h1 = f2bf(av.y), h2 = f2bf(av.z), h3 = f2bf(av.w);
      unsigned short g0 = f2bf(av.x - bf2f(h0)), g1 = f2bf(av.y - bf2f(h1));
      unsigned short g2 = f2bf(av.z - bf2f(h2)), g3 = f2bf(av.w - bf2f(h3));
      uint32* dh = (uint32*)&sAhi[row * 40 + c4];
      dh[0] = (uint32)h0 | ((uint32)h1 << 16);
      dh[1] = (uint32)h2 | ((uint32)h3 << 16);
      uint32* dl = (uint32*)&sAlo[row * 40 + c4];
      dl[0] = (uint32)g0 | ((uint32)g1 << 16);
      dl[1] = (uint32)g2 | ((uint32)g3 << 16);
    }
#pragma unroll
    for (int q = 0; q < 2; ++q) {
      const int v = tid + q * 256;
      const int k = v >> 4;
      const int n4 = (v & 15) * 4;
      const float4 bv = *(const float4*)(Wxh + (size_t)(k0 + k) * H_ + n0 + n4);
      sB[(n4 + 0) * 40 + k] = f2bf(bv.x);
      sB[(n4 + 1) * 40 + k] = f2bf(bv.y);
      sB[(n4 + 2) * 40 + k] = f2bf(bv.z);
      sB[(n4 + 3) * 40 + k] = f2bf(bv.w);
    }
    __syncthreads();
    const int arow = wave * 16 + l15;
    const short8 ahi = *(const short8*)&sAhi[arow * 40 + l4 * 8];
    const short8 alo = *(const short8*)&sAlo[arow * 40 + l4 * 8];
#pragma unroll
    for (int ct = 0; ct < 4; ++ct) {
      const short8 bf = *(const short8*)&sB[(ct * 16 + l15) * 40 + l4 * 8];
      acc[ct] = mfma_bf16(ahi, bf, acc[ct]);
      acc[ct] = mfma_bf16(alo, bf, acc[ct]);
    }
    __syncthreads();
  }
#pragma unroll
  for (int ct = 0; ct < 4; ++ct) {
    const int n = n0 + ct * 16 + l15;
    const float bias = bh[n];
#pragma unroll
    for (int i = 0; i < 4; ++i) {
      const int m = m0 + wave * 16 + l4 * 4 + i;
      xwH[(size_t)m * H_ + n] = f2bf(acc[ct][i] + bias);
    }
  }
}

// ---------------------------------------------------------------------------
// Recurrence: 64 persistent blocks = 4 batch-groups x 16 col-blocks.
// Block: rows rb0..rb0+15, cols c0..c0+63. 4 waves K-split (256 each);
// W_hh bf16 fragments (8x4 short8 = 128 VGPR) in registers all 512 steps.
// h exchange via sc-bit (agent-scope relaxed) loads/stores only.
// Barrier: per-block 64B-padded monotonic flag (1 store, no RMW) + wave-0
// parallel poll of the 16 group flags (1 LLC round-trip per iteration).
// ---------------------------------------------------------------------------
#define NB  16
#define NC  64
#define GCn 16   // col-blocks per batch-group

__global__ __launch_bounds__(256, 1) void rnn_rec(
    const float* __restrict__ Whh,
    unsigned short* __restrict__ xwH,    // [64][512][1024] bf16: in xw, out h
    unsigned short* __restrict__ rotlo,  // [2][64][1024] bf16
    int* __restrict__ ctrl)              // flags: [4 groups][16 blocks][16 ints]
{
  const int blk = blockIdx.x;          // 0..63
  const int gb = blk >> 4;             // 0..3  batch-group
  const int gc = blk & 15;             // 0..15 col-block
  const int rb0 = gb * NB;
  const int c0 = gc * NC;
  const int tid = threadIdx.x;
  const int wave = tid >> 6, lane = tid & 63;
  const int l15 = lane & 15, l4 = lane >> 4;
  const int kp0 = wave * 256;          // K-range of this wave

  __shared__ __align__(16) float red[4][NB][NC];

  // --- W_hh bf16 fragments in registers for all 512 steps ---
  short8 Wf[8][4];
#pragma unroll
  for (int ks = 0; ks < 8; ++ks) {
#pragma unroll
    for (int ct = 0; ct < 4; ++ct) {
      const int n = c0 + ct * 16 + l15;
#pragma unroll
      for (int j = 0; j < 8; ++j) {
        const int k = kp0 + ks * 32 + l4 * 8 + j;
        Wf[ks][ct][j] = (short)f2bf(Whh[(size_t)k * H_ + n]);
      }
    }
  }

  int* gflags = ctrl + gb * (GCn * 16);      // this group's flag array
  int* myflag = gflags + gc * 16;            // 64 B apart

  // epilogue mapping: thread -> (row er, col quad c4) of the 16x64 tile
  const int er = tid >> 4;             // 0..15
  const int c4 = (tid & 15) * 4;       // 0,4,..,60

  for (int t = 0; t < T_; ++t) {
    // xw for this step (plain load — only g1 ever wrote these lines)
    const size_t aXW = ((size_t)((rb0 + er) * T_ + t)) * H_ + c0 + c4;
    const u64 xwu = *(const u64*)(xwH + aXW);

    f32x4 acc[4] = { {0.f,0.f,0.f,0.f}, {0.f,0.f,0.f,0.f},
                     {0.f,0.f,0.f,0.f}, {0.f,0.f,0.f,0.f} };
    if (t > 0) {
      const unsigned short* lsrc = rotlo + (size_t)((t - 1) & 1) * (B_ * H_);
      const int brow = rb0 + l15;
      short8 Ahi[8], Alo[8];
#pragma unroll
      for (int ks = 0; ks < 8; ++ks) {
        const int k = kp0 + ks * 32 + l4 * 8;
        Ahi[ks] = aload16(xwH + (size_t)(brow * T_ + (t - 1)) * H_ + k);
        Alo[ks] = aload16(lsrc + (size_t)brow * H_ + k);
      }
#pragma unroll
      for (int ks = 0; ks < 8; ++ks) {
#pragma unroll
        for (int ct = 0; ct < 4; ++ct) {
          acc[ct] = mfma_bf16(Ahi[ks], Wf[ks][ct], acc[ct]);
          acc[ct] = mfma_bf16(Alo[ks], Wf[ks][ct], acc[ct]);
        }
      }
    }
    // K-partials to LDS (C layout: col=lane&15, row=(lane>>4)*4+i)
#pragma unroll
    for (int ct = 0; ct < 4; ++ct) {
#pragma unroll
      for (int i = 0; i < 4; ++i) {
        red[wave][l4 * 4 + i][ct * 16 + l15] = acc[ct][i];
      }
    }
    __syncthreads();
    // reduce 4 wave-partials + xw, tanh, split hi/lo, coherent u64 stores
    {
      float s[4] = {0.f, 0.f, 0.f, 0.f};
#pragma unroll
      for (int w = 0; w < 4; ++w) {
        const f32x4 v = *(const f32x4*)&red[w][er][c4];
#pragma unroll
        for (int j = 0; j < 4; ++j) s[j] += v[j];
      }
      u64 hi64 = 0, lo64 = 0;
#pragma unroll
      for (int j = 0; j < 4; ++j) {
        const float xwj = bf2f((unsigned short)((xwu >> (16 * j)) & 0xffffu));
        const float h = tanhf(s[j] + xwj);
        const unsigned short hh = f2bf(h);
        const unsigned short hl = f2bf(h - bf2f(hh));
        hi64 |= ((u64)hh) << (16 * j);
        lo64 |= ((u64)hl) << (16 * j);
      }
      __hip_atomic_store((u64*)(xwH + aXW), hi64,
                         __ATOMIC_RELAXED, __HIP_MEMORY_SCOPE_AGENT);
      unsigned short* ldst = rotlo + (size_t)(t & 1) * (B_ * H_);
      __hip_atomic_store((u64*)(ldst + (size_t)(rb0 + er) * H_ + c0 + c4), lo64,
                         __ATOMIC_RELAXED, __HIP_MEMORY_SCOPE_AGENT);
    }
    // --- barrier: drain stores, publish own flag, parallel-poll group ---
    asm volatile("s_waitcnt vmcnt(0)" ::: "memory");
    __syncthreads();                    // all waves' stores drained
    if (tid == 0) {
      __hip_atomic_store(myflag, t + 1, __ATOMIC_RELAXED, __HIP_MEMORY_SCOPE_AGENT);
    }
    if (wave == 0) {
      const int want = t + 1;
      const int* fp = gflags + (lane & 15) * 16;   // 16 flags, 4-fold dup
      int v;
      do {
        v = __hip_atomic_load(fp, __ATOMIC_RELAXED, __HIP_MEMORY_SCOPE_AGENT);
        if (__all(v >= want)) break;
        __builtin_amdgcn_s_sleep(1);
      } while (true);
    }
    __syncthreads();
  }
}

// ---------------------------------------------------------------------------
// GEMM3: out[m][n] = Hm[m][:] @ W_hy[:, n] + b_y[n]   (m = b*512+t, natural)
// ---------------------------------------------------------------------------
__global__ __launch_bounds__(256) void g3_hy(
    const unsigned short* __restrict__ Hm, const float* __restrict__ Why,
    const float* __restrict__ by, float* __restrict__ out)
{
  const int blk = blockIdx.x;
  const int mt = blk >> 3;          // 512 m-tiles
  const int nt = blk & 7;           // 8 n-tiles
  const int m0 = mt * 64, n0 = nt * 64;
  const int tid = threadIdx.x;
  const int wave = tid >> 6, lane = tid & 63;
  const int l15 = lane & 15, l4 = lane >> 4;

  __shared__ unsigned short sA[64 * 40];
  __shared__ unsigned short sB[64 * 40];

  f32x4 acc[4] = { {0.f,0.f,0.f,0.f}, {0.f,0.f,0.f,0.f},
                   {0.f,0.f,0.f,0.f}, {0.f,0.f,0.f,0.f} };

  for (int kk = 0; kk < H_ / 32; ++kk) {
    const int k0 = kk * 32;
    {
      const int row = tid >> 2;
      const int c8 = (tid & 3) * 8;
      const short8 v = *(const short8*)(Hm + (size_t)(m0 + row) * H_ + k0 + c8);
      *(short8*)&sA[row * 40 + c8] = v;
    }
#pragma unroll
    for (int q = 0; q < 2; ++q) {
      const int v = tid + q * 256;
      const int k = v >> 4;
      const int n4 = (v & 15) * 4;
      const float4 bv = *(const float4*)(Why + (size_t)(k0 + k) * O_ + n0 + n4);
      sB[(n4 + 0) * 40 + k] = f2bf(bv.x);
      sB[(n4 + 1) * 40 + k] = f2bf(bv.y);
      sB[(n4 + 2) * 40 + k] = f2bf(bv.z);
      sB[(n4 + 3) * 40 + k] = f2bf(bv.w);
    }
    __syncthreads();
    const short8 a = *(const short8*)&sA[(wave * 16 + l15) * 40 + l4 * 8];
#pragma unroll
    for (int ct = 0; ct < 4; ++ct) {
      const short8 bf = *(const short8*)&sB[(ct * 16 + l15) * 40 + l4 * 8];
      acc[ct] = mfma_bf16(a, bf, acc[ct]);
    }
    __syncthreads();
  }
#pragma unroll
  for (int ct = 0; ct < 4; ++ct) {
    const int n = n0 + ct * 16 + l15;
    const float bias = by[n];
#pragma unroll
    for (int i = 0; i < 4; ++i) {
      const int m = m0 + wave * 16 + l4 * 4 + i;
      out[(size_t)m * O_ + n] = acc[ct][i] + bias;
    }
  }
}

// ---------------------------------------------------------------------------
extern "C" void kernel_launch(void* const* d_in, const int* in_sizes, int n_in,
                              void* d_out, int out_size, void* d_ws, size_t ws_size,
                              hipStream_t stream) {
  const float* x   = (const float*)d_in[0];
  const float* Wxh = (const float*)d_in[1];
  const float* Whh = (const float*)d_in[2];
  const float* bh  = (const float*)d_in[3];
  const float* Why = (const float*)d_in[4];
  const float* by  = (const float*)d_in[5];
  float* out = (float*)d_out;

  // ws layout: xwH (67,108,864 B) | rotlo (262,144 B) | ctrl flags (4,096 B)
  unsigned short* xwH   = (unsigned short*)d_ws;
  unsigned short* rotlo = (unsigned short*)((char*)d_ws + 67108864);
  int*            ctrl  = (int*)((char*)d_ws + 67108864 + 262144);

  hipMemsetAsync(ctrl, 0, 4096, stream);
  g1_xh<<<8192, 256, 0, stream>>>(x, Wxh, bh, xwH);
  rnn_rec<<<64, 256, 0, stream>>>(Whh, xwH, rotlo, ctrl);
  g3_hy<<<4096, 256, 0, stream>>>(xwH, Why, by, out);
}